// Round 9
// baseline (200.021 us; speedup 1.0000x reference)
//
#include <hip/hip_runtime.h>
#include <hip/hip_bf16.h>

#define E_TOT 200000
#define NZ 64
#define ATTR_D 768
#define HID_D 128
#define NCLS 5

typedef __attribute__((ext_vector_type(8))) short short8;   // 8 bf16 (4 VGPRs)
typedef __attribute__((ext_vector_type(4))) float f32x4;    // MFMA accumulator

typedef __attribute__((address_space(3))) unsigned       lds_u32_t;
typedef const __attribute__((address_space(1))) unsigned glob_u32_t;

__device__ __forceinline__ unsigned pk2(float a, float b) {
    __hip_bfloat162 h = __float22bfloat162_rn(make_float2(a, b));
    return *reinterpret_cast<unsigned*>(&h);
}

__device__ __forceinline__ short8 pack8(const float4 x0, const float4 x1) {
    union { unsigned u[4]; short8 s; } r;
    r.u[0] = pk2(x0.x, x0.y);
    r.u[1] = pk2(x0.z, x0.w);
    r.u[2] = pk2(x1.x, x1.y);
    r.u[3] = pk2(x1.z, x1.w);
    return r.s;
}

// ---- prep: W1 [832][128] f32 -> frag-ordered bf16 w1f[kt][f][lane][8]
__global__ void prep_w1f(const float* __restrict__ W1, __hip_bfloat16* __restrict__ w1f) {
    int idx = blockIdx.x * 256 + threadIdx.x;       // 26*8*64*8 = 106496
    if (idx >= 26 * 8 * 64 * 8) return;
    int j    = idx & 7;
    int lane = (idx >> 3) & 63;
    int f    = (idx >> 9) & 7;
    int kt   = idx >> 12;
    int n = f * 16 + (lane & 15);
    int k = kt * 32 + (lane >> 4) * 8 + j;
    w1f[idx] = __float2bfloat16(W1[(size_t)k * HID_D + n]);
}

// ---- main: wave-independent barrier-free ring-3 pipeline at 3 blocks/CU.
// 128 edges/block, 4 waves x 32 rows, 48 KB LDS -> 12 waves/CU (occupancy test:
// R3..R8 all ran 8 waves/CU and cluster at 174-207 us => concurrency-capped).
// Counted vmcnt per iter keeps 2 stages (8 KB/wave) in flight; stage offsets
// folded into the global pointer (builtin imm must stay 0 — R7 failure).
__global__ __launch_bounds__(256, 3) void gcn_main(
    const float* __restrict__ z, const int* __restrict__ ei,
    const float* __restrict__ attr, const __hip_bfloat16* __restrict__ w1f,
    const float* __restrict__ b1, const float* __restrict__ W2,
    const float* __restrict__ b2, float* __restrict__ out) {

    __shared__ float As[3][4096];   // 3 bufs x (4 waves x 32 rows x 32 f32) = 48 KB

    const int t    = threadIdx.x;
    const int wv   = t >> 6;
    const int lane = t & 63;
    const int g    = lane >> 4;     // k-group
    const int c0   = lane & 15;
    const int e0   = blockIdx.x * 128;

    // ---- staging sources (wave-local 32 rows). Lane covers slice-local row
    // rsl = i*8 + (lane>>3), physical 16B chunk lane&7. LDS dest linear; the
    // chunk swizzle (logical = physical ^ (row&7)) goes on the GLOBAL source —
    // a permutation WITHIN each 128B line, so line-coalescing is preserved.
    const float* sbase[4];
#pragma unroll
    for (int i = 0; i < 4; ++i) {
        int rsl = i * 8 + (lane >> 3);
        int cch = (lane & 7) ^ (rsl & 7);
        int er  = e0 + wv * 32 + rsl; if (er >= E_TOT) er = E_TOT - 1;
        sbase[i] = attr + (size_t)er * ATTR_D + cch * 4;
    }

#define SB __builtin_amdgcn_sched_barrier(0)
#define WAITVM(N) asm volatile("s_waitcnt vmcnt(" #N ")" ::: "memory")
#define STAGE(BUF, S)                                                          \
    {                                                                          \
        _Pragma("unroll")                                                      \
        for (int i = 0; i < 4; ++i)                                            \
            __builtin_amdgcn_global_load_lds(                                  \
                (glob_u32_t*)(sbase[i] + (S) * 32),                            \
                (lds_u32_t*)&As[BUF][wv * 1024 + i * 256],                     \
                16, 0, 0);                                                     \
    }

    const __hip_bfloat16* wf = w1f + (size_t)lane * 8;
    auto LOADB = [&](int kt, short8(&b)[8]) {
#pragma unroll
        for (int f = 0; f < 8; ++f)
            b[f] = *reinterpret_cast<const short8*>(wf + (size_t)(kt * 8 + f) * 512);
    };

    // ---- prologue: attr stream first (independent of ei)
    STAGE(0, 0); SB;
    STAGE(1, 1); SB;

    f32x4 acc[2][8];
#pragma unroll
    for (int m = 0; m < 2; ++m)
#pragma unroll
        for (int f = 0; f < 8; ++f) acc[m][f] = (f32x4){0.f, 0.f, 0.f, 0.f};

    // ---- z-phase, register-lean: single B set, per-kt z loads.
    {
        const float* zsp[2];
        const float* zdp[2];
#pragma unroll
        for (int m = 0; m < 2; ++m) {
            int e = e0 + wv * 32 + m * 16 + c0; if (e >= E_TOT) e = E_TOT - 1;
            zsp[m] = z + (size_t)ei[e] * NZ + g * 8;
            zdp[m] = z + (size_t)ei[E_TOT + e] * NZ + g * 8;
        }
        short8 bzz[8];
#pragma unroll
        for (int kt = 0; kt < 2; ++kt) {
            LOADB(kt, bzz);
            short8 a[2];
#pragma unroll
            for (int m = 0; m < 2; ++m) {
                float4 s0 = *reinterpret_cast<const float4*>(zsp[m] + kt * 32);
                float4 s1 = *reinterpret_cast<const float4*>(zsp[m] + kt * 32 + 4);
                float4 d0 = *reinterpret_cast<const float4*>(zdp[m] + kt * 32);
                float4 d1 = *reinterpret_cast<const float4*>(zdp[m] + kt * 32 + 4);
                float4 x0, x1;
                x0.x = s0.x * d0.x; x0.y = s0.y * d0.y; x0.z = s0.z * d0.z; x0.w = s0.w * d0.w;
                x1.x = s1.x * d1.x; x1.y = s1.y * d1.y; x1.z = s1.z * d1.z; x1.w = s1.w * d1.w;
                a[m] = pack8(x0, x1);
            }
#pragma unroll
            for (int f = 0; f < 8; ++f) {
                acc[0][f] = __builtin_amdgcn_mfma_f32_16x16x32_bf16(a[0], bzz[f], acc[0][f], 0, 0, 0);
                acc[1][f] = __builtin_amdgcn_mfma_f32_16x16x32_bf16(a[1], bzz[f], acc[1][f], 0, 0, 0);
            }
        }
    }

    // ---- B prefetch for stages 0,1 (AFTER all z VMEM: in-order retirement safe)
    short8 bX[8], bY[8];
    SB;
    LOADB(2, bX);   // B(0)
    LOADB(3, bY);   // B(1)
    SB;

    // ---- main loop, 24 stages fully unrolled, ring-3.
    // Iter s: [vmcnt] STAGE(s+2 -> buf (s+2)%3) | ds_read+MFMA stage s | LOADB(B(s+2)).
    // At iter-s top, ops newer than B(s): STAGE(s+1)[4] + LOADB(s+3)[8] = 12.
    // Iter 0: only bY newer than bX -> vmcnt(8). Iter 22: no stage/loadb, still 12
    // newer (iter 21's). Iter 23: newest -> vmcnt(0).
#define ITER_BODY(S, BC)                                                       \
        const float* sl = &As[(S) % 3][wv * 1024];                             \
        int pA = (2 * g) ^ (c0 & 7);                                           \
        int pB = pA ^ 1;                                                       \
        float4 x00 = *reinterpret_cast<const float4*>(sl + c0 * 32 + pA * 4);  \
        float4 x01 = *reinterpret_cast<const float4*>(sl + c0 * 32 + pB * 4);  \
        float4 x10 = *reinterpret_cast<const float4*>(sl + (c0 + 16) * 32 + pA * 4); \
        float4 x11 = *reinterpret_cast<const float4*>(sl + (c0 + 16) * 32 + pB * 4); \
        short8 a0 = pack8(x00, x01);                                           \
        short8 a1 = pack8(x10, x11);                                           \
        _Pragma("unroll")                                                      \
        for (int f = 0; f < 8; ++f) {                                          \
            acc[0][f] = __builtin_amdgcn_mfma_f32_16x16x32_bf16(a0, (BC)[f], acc[0][f], 0, 0, 0); \
            acc[1][f] = __builtin_amdgcn_mfma_f32_16x16x32_bf16(a1, (BC)[f], acc[1][f], 0, 0, 0); \
        }

#define ITER_FULL(S, W, BC)                                                    \
    {                                                                          \
        WAITVM(W); SB;                                                         \
        STAGE(((S) + 2) % 3, (S) + 2); SB;                                     \
        ITER_BODY(S, BC)                                                       \
        SB; LOADB((S) + 4, BC); SB;                                            \
    }
#define ITER_BARE(S, W, BC)                                                    \
    {                                                                          \
        WAITVM(W); SB;                                                         \
        ITER_BODY(S, BC)                                                       \
    }

    ITER_FULL(0,  8,  bX) ITER_FULL(1,  12, bY) ITER_FULL(2,  12, bX)
    ITER_FULL(3,  12, bY) ITER_FULL(4,  12, bX) ITER_FULL(5,  12, bY)
    ITER_FULL(6,  12, bX) ITER_FULL(7,  12, bY) ITER_FULL(8,  12, bX)
    ITER_FULL(9,  12, bY) ITER_FULL(10, 12, bX) ITER_FULL(11, 12, bY)
    ITER_FULL(12, 12, bX) ITER_FULL(13, 12, bY) ITER_FULL(14, 12, bX)
    ITER_FULL(15, 12, bY) ITER_FULL(16, 12, bX) ITER_FULL(17, 12, bY)
    ITER_FULL(18, 12, bX) ITER_FULL(19, 12, bY) ITER_FULL(20, 12, bX)
    ITER_FULL(21, 12, bY)
    ITER_BARE(22, 12, bX)
    ITER_BARE(23, 0,  bY)
#undef ITER_FULL
#undef ITER_BARE
#undef ITER_BODY
#undef STAGE
#undef WAITVM
#undef SB

    // ---- epilogue: h = relu(acc + b1); logits = h @ W2 + b2; softmax; write
    float b1v[8], w2v[8][NCLS];
#pragma unroll
    for (int f = 0; f < 8; ++f) {
        int col = f * 16 + c0;
        b1v[f] = b1[col];
#pragma unroll
        for (int cc = 0; cc < NCLS; ++cc) w2v[f][cc] = W2[col * NCLS + cc];
    }
    float b2v[NCLS];
#pragma unroll
    for (int cc = 0; cc < NCLS; ++cc) b2v[cc] = b2[cc];

#pragma unroll
    for (int m = 0; m < 2; ++m) {
#pragma unroll
        for (int i = 0; i < 4; ++i) {
            float lg[NCLS] = {0.f, 0.f, 0.f, 0.f, 0.f};
#pragma unroll
            for (int f = 0; f < 8; ++f) {
                float h = acc[m][f][i] + b1v[f];
                h = fmaxf(h, 0.f);
#pragma unroll
                for (int cc = 0; cc < NCLS; ++cc) lg[cc] = fmaf(h, w2v[f][cc], lg[cc]);
            }
#pragma unroll
            for (int mask = 1; mask < 16; mask <<= 1) {
#pragma unroll
                for (int cc = 0; cc < NCLS; ++cc) lg[cc] += __shfl_xor(lg[cc], mask);
            }
#pragma unroll
            for (int cc = 0; cc < NCLS; ++cc) lg[cc] += b2v[cc];

            float mx = fmaxf(fmaxf(fmaxf(lg[0], lg[1]), fmaxf(lg[2], lg[3])), lg[4]);
            float q[NCLS];
            float s = 0.f;
#pragma unroll
            for (int cc = 0; cc < NCLS; ++cc) { q[cc] = __expf(lg[cc] - mx); s += q[cc]; }
            float inv = 1.0f / s;
            float num = (c0 == 0) ? q[0] : (c0 == 1) ? q[1] : (c0 == 2) ? q[2]
                      : (c0 == 3) ? q[3] : q[4];
            int eo = e0 + wv * 32 + m * 16 + g * 4 + i;
            if (eo < E_TOT && c0 < NCLS) out[(size_t)eo * NCLS + c0] = num * inv;
        }
    }
}

extern "C" void kernel_launch(void* const* d_in, const int* in_sizes, int n_in,
                              void* d_out, int out_size, void* d_ws, size_t ws_size,
                              hipStream_t stream) {
    const float* z    = (const float*)d_in[0];
    const int*   ei   = (const int*)d_in[1];
    const float* attr = (const float*)d_in[2];
    const float* W1   = (const float*)d_in[3];
    const float* b1   = (const float*)d_in[4];
    const float* W2   = (const float*)d_in[5];
    const float* b2   = (const float*)d_in[6];
    float* out = (float*)d_out;
    __hip_bfloat16* w1f = (__hip_bfloat16*)d_ws;   // 26*8*64*8*2 = 212992 B

    prep_w1f<<<(26 * 8 * 64 * 8 + 255) / 256, 256, 0, stream>>>(W1, w1f);
    const int nblk = (E_TOT + 127) / 128;   // 1563
    gcn_main<<<nblk, 256, 0, stream>>>(z, ei, attr, w1f, b1, W2, b2, out);
}